// Round 3
// baseline (149.581 us; speedup 1.0000x reference)
//
#include <hip/hip_runtime.h>
#include <math.h>

// Problem constants
#define B_   8
#define C_   64
#define O_   64
#define H_   128
#define W_   128
#define HW_  (H_ * W_)
#define KSZ  576            // C_*9 contraction length

typedef _Float16 f16x8 __attribute__((ext_vector_type(8)));
typedef float    f32x4 __attribute__((ext_vector_type(4)));

#define WPM_BYTES (18 * 4 * 64 * 8 * 2)   // 73728
#define WPA_BYTES (18 * 2 * 64 * 8 * 2)   // 36864
#define TB2_      (B_ * HW_ / 128)        // 1024 transpose tiles (128 px x 64 ch)

// ---------------------------------------------------------------------------
// Prep kernel (unchanged — vectorized transpose + weight prepack).
// ---------------------------------------------------------------------------
__global__ __launch_bounds__(256) void prep_kernel(
    const float* __restrict__ x,
    const float* __restrict__ offw, const float* __restrict__ modw,
    const float* __restrict__ wgt,
    _Float16* __restrict__ xT, _Float16* __restrict__ wpM, _Float16* __restrict__ wpA)
{
    const int bi = blockIdx.x;
    if (bi < TB2_) {
        __shared__ _Float16 tile[128 * 68];
        const int tid = threadIdx.x;
        const int b      = bi >> 7;
        const int pxbase = (bi & 127) * 128;

        const int px4   = (tid & 31) * 4;
        const int cbase = tid >> 5;
        const float* __restrict__ xp = x + (size_t)b * C_ * HW_ + pxbase;
#pragma unroll
        for (int r = 0; r < 8; ++r) {
            const int c = cbase + r * 8;
            const f32x4 v = *(const f32x4*)&xp[(size_t)c * HW_ + px4];
#pragma unroll
            for (int i = 0; i < 4; ++i)
                tile[(px4 + i) * 68 + c] = (_Float16)v[i];
        }
        __syncthreads();

        const int px = tid >> 1;
        const int c0 = (tid & 1) * 32;
        f16x8 w[4];
#pragma unroll
        for (int q = 0; q < 4; ++q)
#pragma unroll
            for (int j = 0; j < 8; ++j)
                w[q][j] = tile[px * 68 + c0 + q * 8 + j];
        _Float16* __restrict__ op = xT + ((size_t)b * HW_ + pxbase + px) * 64 + c0;
#pragma unroll
        for (int q = 0; q < 4; ++q)
            *(f16x8*)&op[q * 8] = w[q];
        return;
    }
    const int g = (bi - TB2_) * 256 + threadIdx.x;
    if (g < 18 * 4 * 64) {
        const int s = g >> 8, mt = (g >> 6) & 3, lane = g & 63;
        const int k = s >> 1, cb = (s & 1) * 32;
        const int o  = mt * 16 + (lane & 15);
        const int c0 = cb + (lane >> 4) * 8;
        f16x8 v;
#pragma unroll
        for (int j = 0; j < 8; ++j) v[j] = (_Float16)wgt[o * KSZ + (c0 + j) * 9 + k];
        *(f16x8*)&wpM[(size_t)g * 8] = v;
    } else if (g < 18 * 4 * 64 + 18 * 2 * 64) {
        const int u = g - 18 * 4 * 64;
        const int s = u >> 7, mt = (u >> 6) & 1, lane = u & 63;
        const int k = s >> 1, cb = (s & 1) * 32;
        const int t  = mt * 16 + (lane & 15);
        const int c0 = cb + (lane >> 4) * 8;
        f16x8 v;
#pragma unroll
        for (int j = 0; j < 8; ++j) {
            float w = 0.0f;
            if (t < 18)      w = offw[t * KSZ + (c0 + j) * 9 + k];
            else if (t < 27) w = modw[(t - 18) * KSZ + (c0 + j) * 9 + k];
            v[j] = (_Float16)w;
        }
        *(f16x8*)&wpA[(size_t)u * 8] = v;
    }
}

__device__ __forceinline__ f16x8 splat8(_Float16 h) {
    f16x8 v = {h, h, h, h, h, h, h, h};
    return v;
}

// ---------------------------------------------------------------------------
// Fused main kernel (v4 — zero-padded window + full tap precompute).
// r2 lesson: LDS-windowing killed the TA bottleneck (110->57us). Now ~44%
// VALU + ~40% dependency stall. v4:
//  (a) Window staged with ZERO padding (reference zeroes out-of-image
//      VALUES in both convs) -> all boundary clamp/mask logic leaves the
//      hot paths; phase A has no branches at all.
//  (b) All 27 param broadcasts + all 9 taps' bilinear weights, swizzled
//      LDS offsets and window-validity flags precomputed into
//      static-indexed register arrays BEFORE the hot loop. Hot loop is
//      pure {af load, 4x ds_read_b128, rare fallback, pk-f16 combine,
//      4x MFMA} -> scheduler can batch LDS reads across taps.
// Out-of-window corners (P ~ 1e-5): offset forced to 0 (safe read),
// flagged, fixed by predicated global read (zeroed if out-of-image).
// h=1 chunk offset is (elem ^ 32) of the h=0 offset (chunk bit2 <-> bit5).
// ---------------------------------------------------------------------------
#define WROWS 7
#define WCOLS 70

#define PP_IDX(t) (((t) & 3) | (((t) >> 4) << 2))
#define PP_SRC(t) ((((t) & 15) >> 2) * 16)

__global__ __launch_bounds__(256, 2) void dcn_main_kernel(
    const _Float16* __restrict__ xT,    // (B, H, W, C) f16
    const _Float16* __restrict__ wpA,   // packed offset/mod weight frags
    const _Float16* __restrict__ wpM,   // packed main weight frags
    const float* __restrict__ offb,     // (18,)
    const float* __restrict__ modb,     // (9,)
    float* __restrict__ out)            // (B, O, H, W)
{
    __shared__ _Float16 win[WROWS * WCOLS * 64];   // 62720 B

    const int tid  = threadIdx.x;
    const int lane = tid & 63;
    const int wave = tid >> 6;
    const int lq   = lane >> 4;
    const int ln   = lane & 15;

    const int bi  = blockIdx.x;
    const int b   = bi & 7;             // XCD-pinned batch
    const int r2  = bi >> 3;            // 0..255
    const int ho  = r2 >> 1;
    const int x0b = (r2 & 1) * 64;
    const int pxw = wave * 16 + ln;     // px within half-row, 0..63
    const int wo  = x0b + pxw;          // this lane's output x

    const _Float16* __restrict__ xbT = xT + (size_t)b * HW_ * 64;

    // ---------------- Stage window (ZERO-padded): rows ho-3..ho+3 ----------
#pragma unroll
    for (int it = 0; it < 16; ++it) {
        const int e = it * 256 + tid;
        if (e < WROWS * WCOLS * 8) {
            const int r   = e / (WCOLS * 8);
            const int rem = e - r * (WCOLS * 8);
            const int cx  = rem >> 3;
            const int q   = rem & 7;
            const int yr  = ho - 3 + r;
            const int xc  = x0b - 3 + cx;
            f16x8 v = splat8((_Float16)0.0f);
            if (((unsigned)yr < H_) && ((unsigned)xc < W_))
                v = *(const f16x8*)&xbT[((size_t)(yr * W_ + xc)) * 64 + q * 8];
            *(f16x8*)&win[(r * WCOLS + cx) * 64 + ((q ^ (cx & 7)) * 8)] = v;
        }
    }
    __syncthreads();

    // ---------------- Phase A: offset/modulator conv via MFMA (no branches)
    f32x4 accA[2];
#pragma unroll
    for (int mt = 0; mt < 2; ++mt) accA[mt] = (f32x4){0.f, 0.f, 0.f, 0.f};

#pragma unroll
    for (int s = 0; s < 18; ++s) {
        const int k = s >> 1, h = s & 1;
        const int ki = k / 3, kj = k - ki * 3;
        f16x8 afA[2];
#pragma unroll
        for (int mt = 0; mt < 2; ++mt)
            afA[mt] = *(const f16x8*)&wpA[(size_t)((s * 2 + mt) * 64 + lane) * 8];
        const int sy = ki + 2;
        const int sx = pxw + kj + 2;
        const int chunk = h * 4 + lq;
        const f16x8 bfA = *(const f16x8*)&win[(sy * WCOLS + sx) * 64 + ((chunk ^ (sx & 7)) * 8)];
#pragma unroll
        for (int mt = 0; mt < 2; ++mt)
            accA[mt] = __builtin_amdgcn_mfma_f32_16x16x32_f16(afA[mt], bfA, accA[mt], 0, 0, 0);
    }

    // Params in registers: lane (lq,ln) owns t = mt*16 + lq*4 + r for px ln.
    float pp[8];
#pragma unroll
    for (int mt = 0; mt < 2; ++mt)
#pragma unroll
        for (int r = 0; r < 4; ++r) {
            const int t = mt * 16 + lq * 4 + r;
            const float val = accA[mt][r];
            float o = 0.0f;
            if (t < 18)      o = val + offb[t];
            else if (t < 27) o = 2.0f / (1.0f + expf(-(val + modb[t - 18])));
            pp[mt * 4 + r] = o;
        }

    // ---------------- Phase B precompute: params, weights, offsets ---------
    float dyk[9], dxk[9], mkk[9];
#pragma unroll
    for (int k = 0; k < 9; ++k) {
        dyk[k] = __shfl(pp[PP_IDX(2 * k)],     PP_SRC(2 * k) + ln, 64);
        dxk[k] = __shfl(pp[PP_IDX(2 * k + 1)], PP_SRC(2 * k + 1) + ln, 64);
        mkk[k] = __shfl(pp[PP_IDX(18 + k)],    PP_SRC(18 + k) + ln, 64);
    }

    float w00k[9], w01k[9], w10k[9], w11k[9];
    int   b00k[9], b01k[9], b10k[9], b11k[9];
    int   ok00k[9], ok01k[9], ok10k[9], ok11k[9];
    int   y0k[9], x0k[9];
#pragma unroll
    for (int k = 0; k < 9; ++k) {
        const int ki = k / 3, kj = k - ki * 3;
        const float ys = (float)(ho - 1 + ki) + dyk[k];
        const float xs = (float)(wo - 1 + kj) + dxk[k];
        const float y0f = floorf(ys), x0f = floorf(xs);
        const float wy = ys - y0f, wx = xs - x0f;
        const int y0 = (int)y0f, x0 = (int)x0f;
        y0k[k] = y0; x0k[k] = x0;
        const float mk  = mkk[k];
        const float wyc = 1.0f - wy, wxc = 1.0f - wx;
        w00k[k] = wyc * wxc * mk;
        w01k[k] = wyc * wx  * mk;
        w10k[k] = wy  * wxc * mk;
        w11k[k] = wy  * wx  * mk;
        const int sy0 = y0 - ho + 3, sy1 = sy0 + 1;
        const int sx0 = x0 - x0b + 3, sx1 = sx0 + 1;
        const int oy0 = (unsigned)sy0 < WROWS, oy1 = (unsigned)sy1 < WROWS;
        const int ox0 = (unsigned)sx0 < WCOLS, ox1 = (unsigned)sx1 < WCOLS;
        ok00k[k] = oy0 & ox0; ok01k[k] = oy0 & ox1;
        ok10k[k] = oy1 & ox0; ok11k[k] = oy1 & ox1;
        const int r0 = sy0 * WCOLS, r1 = sy1 * WCOLS;
        const int e00 = (r0 + sx0) * 64 + ((lq ^ (sx0 & 7)) * 8);
        const int e01 = (r0 + sx1) * 64 + ((lq ^ (sx1 & 7)) * 8);
        const int e10 = (r1 + sx0) * 64 + ((lq ^ (sx0 & 7)) * 8);
        const int e11 = (r1 + sx1) * 64 + ((lq ^ (sx1 & 7)) * 8);
        b00k[k] = ok00k[k] ? e00 : 0;
        b01k[k] = ok01k[k] ? e01 : 0;
        b10k[k] = ok10k[k] ? e10 : 0;
        b11k[k] = ok11k[k] ? e11 : 0;
    }

    // ---------------- Phase B hot loop: reads + combine + MFMA -------------
    f32x4 acc[4];
#pragma unroll
    for (int mt = 0; mt < 4; ++mt) acc[mt] = (f32x4){0.f, 0.f, 0.f, 0.f};

#pragma unroll
    for (int k = 0; k < 9; ++k) {
        const f16x8 w00v = splat8((_Float16)w00k[k]);
        const f16x8 w01v = splat8((_Float16)w01k[k]);
        const f16x8 w10v = splat8((_Float16)w10k[k]);
        const f16x8 w11v = splat8((_Float16)w11k[k]);

#pragma unroll
        for (int h = 0; h < 2; ++h) {
            const int s  = 2 * k + h;
            const int hx = h << 5;            // elem-offset XOR for chunk bit2
            const int c0 = h * 32 + lq * 8;   // fallback channel base

            f16x8 af[4];
#pragma unroll
            for (int mt = 0; mt < 4; ++mt)
                af[mt] = *(const f16x8*)&wpM[(size_t)((s * 4 + mt) * 64 + lane) * 8];

            f16x8 a00 = *(const f16x8*)&win[b00k[k] ^ hx];
            f16x8 a01 = *(const f16x8*)&win[b01k[k] ^ hx];
            f16x8 a10 = *(const f16x8*)&win[b10k[k] ^ hx];
            f16x8 a11 = *(const f16x8*)&win[b11k[k] ^ hx];

            // rare fallback: corner outside window (value zeroed if outside image)
            if (__builtin_expect(!ok00k[k], 0)) {
                const int yc = min(max(y0k[k], 0), H_ - 1), xc = min(max(x0k[k], 0), W_ - 1);
                const bool in = ((unsigned)y0k[k] < H_) && ((unsigned)x0k[k] < W_);
                a00 = in ? *(const f16x8*)&xbT[((size_t)(yc * W_ + xc)) * 64 + c0] : splat8((_Float16)0.0f);
            }
            if (__builtin_expect(!ok01k[k], 0)) {
                const int yc = min(max(y0k[k], 0), H_ - 1), xc = min(max(x0k[k] + 1, 0), W_ - 1);
                const bool in = ((unsigned)y0k[k] < H_) && ((unsigned)(x0k[k] + 1) < W_);
                a01 = in ? *(const f16x8*)&xbT[((size_t)(yc * W_ + xc)) * 64 + c0] : splat8((_Float16)0.0f);
            }
            if (__builtin_expect(!ok10k[k], 0)) {
                const int yc = min(max(y0k[k] + 1, 0), H_ - 1), xc = min(max(x0k[k], 0), W_ - 1);
                const bool in = ((unsigned)(y0k[k] + 1) < H_) && ((unsigned)x0k[k] < W_);
                a10 = in ? *(const f16x8*)&xbT[((size_t)(yc * W_ + xc)) * 64 + c0] : splat8((_Float16)0.0f);
            }
            if (__builtin_expect(!ok11k[k], 0)) {
                const int yc = min(max(y0k[k] + 1, 0), H_ - 1), xc = min(max(x0k[k] + 1, 0), W_ - 1);
                const bool in = ((unsigned)(y0k[k] + 1) < H_) && ((unsigned)(x0k[k] + 1) < W_);
                a11 = in ? *(const f16x8*)&xbT[((size_t)(yc * W_ + xc)) * 64 + c0] : splat8((_Float16)0.0f);
            }

            f16x8 r = a00 * w00v;
            r = a01 * w01v + r;
            r = a10 * w10v + r;
            r = a11 * w11v + r;

#pragma unroll
            for (int mt = 0; mt < 4; ++mt)
                acc[mt] = __builtin_amdgcn_mfma_f32_16x16x32_f16(af[mt], r, acc[mt], 0, 0, 0);
        }
    }

    // Epilogue B: D col = ln -> px, row = o.
    float* __restrict__ ob = out + (size_t)b * O_ * HW_ + (size_t)ho * W_;
#pragma unroll
    for (int mt = 0; mt < 4; ++mt)
#pragma unroll
        for (int r = 0; r < 4; ++r) {
            const int o = mt * 16 + lq * 4 + r;
            ob[(size_t)o * HW_ + wo] = acc[mt][r];
        }
}

extern "C" void kernel_launch(void* const* d_in, const int* in_sizes, int n_in,
                              void* d_out, int out_size, void* d_ws, size_t ws_size,
                              hipStream_t stream) {
    (void)in_sizes; (void)n_in; (void)out_size; (void)ws_size;
    const float* x    = (const float*)d_in[0];
    const float* offw = (const float*)d_in[1];
    const float* offb = (const float*)d_in[2];
    const float* modw = (const float*)d_in[3];
    const float* modb = (const float*)d_in[4];
    const float* wgt  = (const float*)d_in[5];
    float* out = (float*)d_out;

    _Float16* wpM = (_Float16*)d_ws;                                   // 73728 B
    _Float16* wpA = (_Float16*)((char*)d_ws + WPM_BYTES);              // 36864 B
    _Float16* xT  = (_Float16*)((char*)d_ws + WPM_BYTES + WPA_BYTES);  // 16.78 MB

    prep_kernel<<<TB2_ + 27, 256, 0, stream>>>(x, offw, modw, wgt, xT, wpM, wpA);
    dcn_main_kernel<<<B_ * H_ * 2, 256, 0, stream>>>(xT, wpA, wpM, offb, modb, out);
}